// Round 9
// baseline (242.704 us; speedup 1.0000x reference)
//
#include <hip/hip_runtime.h>
#include <hip/hip_bf16.h>

// MultiHeadAttention: B=2, S=2048, H=16, d=64, D=1024. I/O fp32; compute bf16 MFMA.
// [cvt] fp32->bf16 of W+biases ONLY -> [qkv] X@W^T+b reading X directly as fp32
// with 2-DEEP register-pipelined in-register conversion (r18) -> [attn] flash
// attn, swapped QK^T, in-register P, key-half split -> [proj] O@Wo^T+bo.
// r13 (kept): XCD working-set swizzles — per-XCD concurrent set <=4MB.
// r14 (kept): gemm_tile one barrier/kt, NB=3 rotation, counted vmcnt.
// r16 (kept): attn key-half split (46us; all 4 SIMDs busy every kt).
// r18: r17's fused X-cvt regressed because the X-load->cvt->ds_write chain had
// only one MFMA-phase of slack AND fp32 X (6MB/XCD > 4MB L2) runs at HBM
// latency. Now X(kt+2) loads issue in region kt into alternating reg sets
// (xa/xb by tile parity, static names); X(kt+1) is cvt+ds_written pre-barrier
// (NB=3 makes that safe); vmcnt(6) retires exactly {W(kt), X(kt+1)} (audit:
// 12 outstanding = W(kt)2 + X(kt+1)4 + W(kt+1)2 + X(kt+2)4). ~1.5 regions of
// load slack >> 900cy HBM latency.
// LAW (r7/r8): MFMA fragments are lane-granular gathers -> always read them from
// LDS; keep all global accesses contiguous (staging loads / scatter stores only).

typedef unsigned short u16;
typedef __attribute__((ext_vector_type(8))) short short8;   // 8 bf16 (MFMA A/B frag)
typedef __attribute__((ext_vector_type(4))) float floatx4;  // MFMA C/D frag

__device__ __forceinline__ float bf2f(u16 x) {
  return __uint_as_float(((unsigned)x) << 16);
}
__device__ __forceinline__ u16 f2bf(float f) {
  unsigned x = __float_as_uint(f);
  return (u16)((x + 0x7fffu + ((x >> 16) & 1u)) >> 16);  // RNE
}
__device__ __forceinline__ ushort2 pk_bf16(float a, float b) {
  __hip_bfloat162 h2 = __float22bfloat162_rn(make_float2(a, b));  // v_cvt_pk_bf16_f32
  ushort2 u;
  __builtin_memcpy(&u, &h2, 4);
  return u;
}
__device__ __forceinline__ short8 cvt8(float4 a, float4 b) {  // 8 fp32 -> 8 bf16
  const ushort2 p0 = pk_bf16(a.x, a.y), p1 = pk_bf16(a.z, a.w);
  const ushort2 p2 = pk_bf16(b.x, b.y), p3 = pk_bf16(b.z, b.w);
  union { short8 s8; ushort us[8]; } u;
  u.us[0] = p0.x; u.us[1] = p0.y; u.us[2] = p1.x; u.us[3] = p1.y;
  u.us[4] = p2.x; u.us[5] = p2.y; u.us[6] = p3.x; u.us[7] = p3.y;
  return u.s8;
}
#if __has_builtin(__builtin_amdgcn_exp2f)
#define EXP2(x) __builtin_amdgcn_exp2f(x)
#else
#define EXP2(x) exp2f(x)
#endif
__device__ __forceinline__ void gll16(const u16* g, u16* lds) {
  __builtin_amdgcn_global_load_lds((const __attribute__((address_space(1))) void*)g,
                                   (__attribute__((address_space(3))) void*)lds,
                                   16, 0, 0);
}

// ---------------------------------------------------------------------------
// fp32 -> bf16 of the 4 weight matrices + 4 biases (X no longer staged).
// 4100 blocks x 256 thr x 4 elem = 4,198,400 elements, exact cover.
// ---------------------------------------------------------------------------
__global__ __launch_bounds__(256) void cvt_kernel(
    const float* __restrict__ wq, const float* __restrict__ wk,
    const float* __restrict__ wv, const float* __restrict__ wo,
    const float* __restrict__ bq, const float* __restrict__ bk,
    const float* __restrict__ bv, const float* __restrict__ bo,
    u16* __restrict__ ws) {
  const int i4 = (blockIdx.x * 256 + threadIdx.x) * 4;
  const float* src;
  u16* dst;
  int local;
  if (i4 < 1048576)       { src = wq; dst = ws + 12582912; local = i4; }
  else if (i4 < 2097152)  { src = wk; dst = ws + 13631488; local = i4 - 1048576; }
  else if (i4 < 3145728)  { src = wv; dst = ws + 14680064; local = i4 - 2097152; }
  else if (i4 < 4194304)  { src = wo; dst = ws + 15728640; local = i4 - 3145728; }
  else if (i4 < 4195328)  { src = bq; dst = ws + 16777216; local = i4 - 4194304; }
  else if (i4 < 4196352)  { src = bk; dst = ws + 16779264; local = i4 - 4195328; }
  else if (i4 < 4197376)  { src = bv; dst = ws + 16781312; local = i4 - 4196352; }
  else                    { src = bo; dst = ws + 16783360; local = i4 - 4197376; }
  const float4 f = *(const float4*)(src + local);
  ushort4 o;
  o.x = f2bf(f.x); o.y = f2bf(f.y); o.z = f2bf(f.z); o.w = f2bf(f.w);
  *(ushort4*)(dst + local) = o;
}

// ---------------------------------------------------------------------------
// GEMM tile: out[m][n] = (X[m][:].W[n][:] + bias[n]) * oscale
// MTILE x 128 tile, 256 thr (2x2 waves), BK=32. W staged via gll16 (bf16).
// XF32=true (qkv): X read as fp32 from the ORIGINAL inputs with a 2-DEEP
//   register pipeline: region kt issues X(kt+2) loads into the alternate reg
//   set; X(kt+1) (loaded a full region ago) is cvt8'd and ds_written into
//   buf (kt+1)%3 pre-barrier. vmcnt(6) retires exactly {W(kt), X(kt+1)}.
// XF32=false (proj): X staged via gll16 (bf16).
// r14 schedule: NB=3, stage-ahead 1, ONE s_barrier per kt, counted vmcnt.
// Region safety: between barrier(kt) and barrier(kt+1) the block reads buf
// kt%3 and writes buf (kt+1)%3 — disjoint (mod 3; pre-barrier writes also
// avoid the laggards' buf (kt-1)%3).
// mode 0: bf16 row-major. mode 1: bf16 [b][h][dd][s'] (pi'-key-permuted).
// mode 2: fp32 row-major.
// ---------------------------------------------------------------------------
template <int MTILE, bool XF32>
__device__ __forceinline__ void gemm_tile(
    const u16* __restrict__ X16, const float* __restrict__ X32,
    const u16* __restrict__ W, const u16* __restrict__ bias,
    u16* __restrict__ out16, float* __restrict__ out32,
    int row0, int col0, int mode, float oscale, u16* As, u16* Bs) {
  constexpr int NI = MTILE / 32;      // A-frag repeats per wave (4 or 2)
  constexpr int ABUF = MTILE * 32;    // u16 per A buffer (4096 or 2048)
  const int tid = threadIdx.x;
  const int w = tid >> 6, l = tid & 63;
  const int lan = l & 15, quad = l >> 4;
  const int wm = w & 1, wn = w >> 1;

  floatx4 acc[NI][4];
#pragma unroll
  for (int i = 0; i < NI; ++i)
#pragma unroll
    for (int j = 0; j < 4; ++j) acc[i][j] = (floatx4)0.0f;

  const int r0 = tid >> 2, kq0 = tid & 3;
  const int r1 = (tid + 256) >> 2;
  const int woff = w * 512;
  const u16* Xa0 = XF32 ? nullptr : X16 + (size_t)(row0 + r0) * 1024 + kq0 * 8;
  const float* Xf0 = XF32 ? X32 + (size_t)(row0 + r0) * 1024 + kq0 * 8 : nullptr;
  const float* Xf1 = XF32 ? X32 + (size_t)(row0 + r1) * 1024 + kq0 * 8 : nullptr;
  const u16* Wb0 = W + (size_t)(col0 + r0) * 1024 + kq0 * 8;
  const u16* Wb1 = W + (size_t)(col0 + r1) * 1024 + kq0 * 8;

#define STAGEW(buf, kt)                                          \
  do {                                                           \
    gll16(Wb0 + (kt) * 32, Bs + (buf) * 4096 + woff);            \
    gll16(Wb1 + (kt) * 32, Bs + (buf) * 4096 + 2048 + woff);     \
  } while (0)
#define STAGEXG(buf, kt)                                         \
  do {                                                           \
    gll16(Xa0 + (kt) * 32, As + (buf) * ABUF + woff);            \
  } while (0)
#define LOADX(s, kt)                                             \
  do {                                                           \
    s##0 = *(const float4*)(Xf0 + (kt) * 32);                    \
    s##1 = *(const float4*)(Xf0 + (kt) * 32 + 4);                \
    s##2 = *(const float4*)(Xf1 + (kt) * 32);                    \
    s##3 = *(const float4*)(Xf1 + (kt) * 32 + 4);                \
  } while (0)
#define CVTWR(s, buf)                                            \
  do {                                                           \
    *(short8*)(As + (buf) * ABUF + tid * 8) = cvt8(s##0, s##1);  \
    *(short8*)(As + (buf) * ABUF + 2048 + tid * 8) = cvt8(s##2, s##3); \
  } while (0)

  float4 xa0, xa1, xa2, xa3, xb0, xb1, xb2, xb3;  // 2-deep X pipeline (XF32)
  if constexpr (XF32) {
    LOADX(xa, 0);             // X(0) {4}
    STAGEW(0, 0);             // W(0) {2}
    LOADX(xb, 1);             // X(1) {4}  -> 10 outstanding
    __asm__ volatile("s_waitcnt vmcnt(6)" ::: "memory");  // retire X(0)
    CVTWR(xa, 0);             // X(0) -> buf0 (visible via iter-0 lgkmcnt)
  } else {
    STAGEXG(0, 0);
    STAGEW(0, 0);
  }
  int cur = 0;
  for (int kt = 0; kt < 32; ++kt) {
    const int nb = cur == 2 ? 0 : cur + 1;  // (kt+1)%3
    if constexpr (XF32) {
      if (kt <= 30) {
        STAGEW(nb, kt + 1);                 // W(kt+1) {2}
        if (kt <= 29) {
          if ((kt & 1) == 0) LOADX(xa, kt + 2);  // X(kt+2) {4}, even tiles->xa
          else               LOADX(xb, kt + 2);
          // outstanding: W(kt)2 + X(kt+1)4 + W(kt+1)2 + X(kt+2)4 = 12
          __asm__ volatile("s_waitcnt vmcnt(6)" ::: "memory");  // retire W(kt),X(kt+1)
        } else {  // kt == 30: no X(32). outstanding: W(30)2+X(31)4+W(31)2 = 8
          __asm__ volatile("s_waitcnt vmcnt(2)" ::: "memory");
        }
        if ((kt & 1) == 0) CVTWR(xb, nb);   // X(kt+1) (odd) -> buf (kt+1)%3
        else               CVTWR(xa, nb);
        __asm__ volatile("s_waitcnt lgkmcnt(0)" ::: "memory");  // writes visible
      } else {  // kt == 31
        __asm__ volatile("s_waitcnt vmcnt(0) lgkmcnt(0)" ::: "memory");
      }
    } else {
      if (kt < 31) {
        STAGEXG(nb, kt + 1);
        STAGEW(nb, kt + 1);
        __asm__ volatile("s_waitcnt vmcnt(3)" ::: "memory");
      } else {
        __asm__ volatile("s_waitcnt vmcnt(0)" ::: "memory");
      }
    }
    __builtin_amdgcn_s_barrier();  // all waves' staging for tile kt visible

    const u16* Ab = As + cur * ABUF;
    const u16* Bb = Bs + cur * 4096;
    short8 af[NI], bfr[4];
#pragma unroll
    for (int i = 0; i < NI; ++i)
      af[i] = *(const short8*)(Ab + (wm * (MTILE / 2) + i * 16 + lan) * 32 + quad * 8);
#pragma unroll
    for (int j = 0; j < 4; ++j)
      bfr[j] = *(const short8*)(Bb + (wn * 64 + j * 16 + lan) * 32 + quad * 8);
    // no second barrier: compiler inserts lgkm waits for ds_read->MFMA; buffer
    // reuse safety comes from the mod-3 rotation (see header comment).
#pragma unroll
    for (int i = 0; i < NI; ++i)
#pragma unroll
      for (int j = 0; j < 4; ++j)
        acc[i][j] = __builtin_amdgcn_mfma_f32_16x16x32_bf16(af[i], bfr[j], acc[i][j], 0, 0, 0);
    cur = nb;
  }
#undef STAGEW
#undef STAGEXG
#undef LOADX
#undef CVTWR

#pragma unroll
  for (int i = 0; i < NI; ++i) {
    const int mb = row0 + wm * (MTILE / 2) + i * 16 + quad * 4;
#pragma unroll
    for (int j = 0; j < 4; ++j) {
      const int n = col0 + wn * 64 + j * 16 + lan;
      const float bv = bf2f(bias[n]);
      if (mode == 0) {
#pragma unroll
        for (int r = 0; r < 4; ++r)
          out16[(size_t)(mb + r) * 1024 + n] = f2bf((acc[i][j][r] + bv) * oscale);
      } else if (mode == 1) {
        // V head-transposed + pi'-key-permuted: k=s&63 -> slot
        // 32*k[5] + 8*k[3:2] + 4*k[4] + k[1:0]  (key-half h=k[5] -> contiguous
        // cols 32h..32h+31). mb%4==0 -> r=k&3 in LOW bits -> ushort4 store.
        const int b = mb >> 11;
        const int h = n >> 6, dd = n & 63;
        u16* base = out16 + (size_t)((b * 16 + h) * 64 + dd) * 2048;
        const int s0 = mb & 2047;
        const int k0 = s0 & 63;
        const int sp0 = (s0 & ~63) | (((k0 >> 5) & 1) << 5) | (((k0 >> 2) & 3) << 3) |
                        (((k0 >> 4) & 1) << 2);
        ushort4 ov;
        ov.x = f2bf(acc[i][j][0] + bv);
        ov.y = f2bf(acc[i][j][1] + bv);
        ov.z = f2bf(acc[i][j][2] + bv);
        ov.w = f2bf(acc[i][j][3] + bv);
        *(ushort4*)(base + sp0) = ov;
      } else {
#pragma unroll
        for (int r = 0; r < 4; ++r)
          out32[(size_t)(mb + r) * 1024 + n] = acc[i][j][r] + bv;
      }
    }
  }
}

__global__ __launch_bounds__(256) void qkv_kernel(
    const float* __restrict__ xq, const float* __restrict__ xk,
    const float* __restrict__ xv,
    const u16* __restrict__ Wq, const u16* __restrict__ Wk, const u16* __restrict__ Wv,
    const u16* __restrict__ bq, const u16* __restrict__ bk, const u16* __restrict__ bv,
    u16* __restrict__ Qo, u16* __restrict__ Ko, u16* __restrict__ Vto) {
  __shared__ __align__(16) u16 As[3 * 4096];
  __shared__ __align__(16) u16 Bs[3 * 4096];
  // r13 XCD grouping: all 8 col-blocks of one (which,tm) X-panel on ONE XCD.
  const int bx = blockIdx.x;           // 0..767
  const int xcd = bx & 7;
  const int j = bx >> 3;               // 0..95
  const int c = j & 7;                 // col block
  const int gidx = j >> 3;             // 0..11
  const int g = gidx * 8 + xcd;        // group = which*32 + tm, on XCD g%8
  const int which = g >> 5;            // 0=Q 1=K 2=V
  const int tile_m = g & 31;
  const int col0 = c * 128;
  const float* X = which == 0 ? xq : (which == 1 ? xk : xv);
  const u16* W = which == 0 ? Wq : (which == 1 ? Wk : Wv);
  const u16* bias = which == 0 ? bq : (which == 1 ? bk : bv);
  u16* out = which == 0 ? Qo : (which == 1 ? Ko : Vto);
  const float C = 0.125f * 1.4426950408889634f;  // fold scale*log2e into Q
  gemm_tile<128, true>(nullptr, X, W, bias, out, nullptr, tile_m * 128, col0,
                       which == 2 ? 1 : 0, which == 0 ? C : 1.0f, As, Bs);
}

__global__ __launch_bounds__(256) void proj_kernel(
    const u16* __restrict__ X, const u16* __restrict__ W,
    const u16* __restrict__ bias, float* __restrict__ out) {
  // 64x128 tiles -> 512 blocks = 2 blocks/CU. r13 XCD grouping: 8 tm-panels
  // (1MB) + full Wo (2MB) per XCD = 3MB < 4MB L2.
  __shared__ __align__(16) u16 As[3 * 2048];
  __shared__ __align__(16) u16 Bs[3 * 4096];
  const int bx = blockIdx.x;   // 0..511
  const int xcd = bx & 7;
  const int j = bx >> 3;       // 0..63
  const int c = j & 7;
  const int gidx = j >> 3;     // 0..7
  const int tm = xcd * 8 + gidx;
  gemm_tile<64, false>(X, nullptr, W, bias, nullptr, out, tm * 64, c * 128, 2,
                       1.0f, As, Bs);
}

// ---------------------------------------------------------------------------
// Flash attention v12 (r16): swapped QK^T, in-register P, KEY-HALF split.
// grid 512 flat, 256 thr, 4 waves. Wave = (g = w>>1: 64 q rows, h = w&1: keys
// [32h, 32h+32) of EVERY tile). Per wave-kt (64q x 32keys):
//   S^T = mfma(A=K[key][dd], B=Q[q][dd])  16 MFMA, kf 4 b128 reads
//   p = exp2(S^T - 16); cvt_pk -> ONE PV B-frag per mi (permutation pi')
//   O^T += mfma(A=V^T[dd][k'], B=P^T)     16 MFMA, vf 4 b128 reads
// -> 8 b128 / 32 MFMA (2x reuse) with ALL 4 SIMDs active every kt.
// Fixed-max softmax => key-half partials directly addable: epilogue merge via
// LDS (h=1 waves dump unnorm oacc + lrun, h=0 partner w^1 adds, norms, stores).
// K/V LDS double-buffered, ONE barrier/kt; staging by all 256 threads.
// LDS: KV[4][64*72] = 36864 B; 2 blocks/CU (8 waves/CU).
// r13 XCD grouping: each XCD owns 4 complete bh -> K/V set 2MB, L2-resident.
// ---------------------------------------------------------------------------
#define FIXMAX 16.0f
#define KPAD 72
__global__ __launch_bounds__(256, 2) void attn_kernel(
    const u16* __restrict__ Q, const u16* __restrict__ K,
    const u16* __restrict__ Vt, u16* __restrict__ O) {
  __shared__ __align__(16) u16 KV[4][64 * KPAD];  // [0..1]=K dbuf, [2..3]=V dbuf
  const int tid = threadIdx.x;
  const int w = tid >> 6, l = tid & 63;
  const int lan = l & 15, quad = l >> 4;
  const int g = w >> 1;   // q-group: rows g*64 .. g*64+63
  const int h2 = w & 1;   // key half: keys 32*h2 .. 32*h2+31 of each tile
  // XCD grouping: flattened id -> (bh, qtile) with 4 full bh per XCD
  const int id = blockIdx.x + (blockIdx.y << 4);  // 0..511, xcd = id&7
  const int xcd = id & 7;
  const int jj = id >> 3;              // 0..63
  const int bh = xcd * 4 + (jj >> 4);  // 4 complete bh per XCD
  const int q0 = (jj & 15) * 128;
  const int b = bh >> 4, h = bh & 15;
  const u16* Qg = Q + (size_t)(b * 2048 + q0) * 1024 + h * 64;
  const u16* Kg = K + (size_t)(b * 2048) * 1024 + h * 64;
  const u16* Vg = Vt + (size_t)((b * 16 + h) * 64) * 2048;

  // Q B-frags direct from global: rows g*64 + mi*16 + lan (contiguous 64B rows)
  short8 qf[4][2];
#pragma unroll
  for (int mi = 0; mi < 4; ++mi)
#pragma unroll
    for (int kk = 0; kk < 2; ++kk)
      qf[mi][kk] = *(const short8*)(Qg + (size_t)(g * 64 + mi * 16 + lan) * 1024 +
                                    kk * 32 + quad * 8);

  float lrun[4] = {0.f, 0.f, 0.f, 0.f};
  floatx4 oacc[4][4];
#pragma unroll
  for (int mi = 0; mi < 4; ++mi)
#pragma unroll
    for (int nd = 0; nd < 4; ++nd) oacc[mi][nd] = (floatx4)0.0f;

  // staging maps: 64 rows x 8 chunks of 16B = 512 chunks, 2/thread (coalesced)
  const int rowA = tid >> 3, colq = (tid & 7) * 8;  // rows 0..31
  const int rowB = rowA + 32;                       // rows 32..63

  // prologue: tile 0 -> regs -> LDS buf 0
  short8 k0 = *(const short8*)(Kg + (size_t)rowA * 1024 + colq);
  short8 k1 = *(const short8*)(Kg + (size_t)rowB * 1024 + colq);
  short8 v0 = *(const short8*)(Vg + (size_t)rowA * 2048 + colq);
  short8 v1 = *(const short8*)(Vg + (size_t)rowB * 2048 + colq);
  *(short8*)(KV[0] + rowA * KPAD + colq) = k0;
  *(short8*)(KV[0] + rowB * KPAD + colq) = k1;
  *(short8*)(KV[2] + rowA * KPAD + colq) = v0;
  *(short8*)(KV[2] + rowB * KPAD + colq) = v1;
  __syncthreads();

  for (int kt = 0; kt < 32; ++kt) {
    const int cur = kt & 1;
    // issue next-tile global loads right after the barrier (all threads):
    // in flight across the compute phase, consumed by reg->LDS writes at end
    if (kt < 31) {
      const int kn = kt + 1;
      k0 = *(const short8*)(Kg + (size_t)(kn * 64 + rowA) * 1024 + colq);
      k1 = *(const short8*)(Kg + (size_t)(kn * 64 + rowB) * 1024 + colq);
      v0 = *(const short8*)(Vg + (size_t)rowA * 2048 + kn * 64 + colq);
      v1 = *(const short8*)(Vg + (size_t)rowB * 2048 + kn * 64 + colq);
    }
    const u16* Kc = KV[cur];
    const u16* Vc = KV[2 + cur];

    // S^T = mfma(A=K, B=Q): kf rows (2*h2+nj2)*16+lan, 2 b128 per kk.
    floatx4 sacc[4][2];
#pragma unroll
    for (int mi = 0; mi < 4; ++mi)
#pragma unroll
      for (int nj2 = 0; nj2 < 2; ++nj2) sacc[mi][nj2] = (floatx4)(-FIXMAX);
#pragma unroll
    for (int kk = 0; kk < 2; ++kk) {
      short8 kf[2];
#pragma unroll
      for (int nj2 = 0; nj2 < 2; ++nj2)
        kf[nj2] = *(const short8*)(Kc + ((2 * h2 + nj2) * 16 + lan) * KPAD +
                                   kk * 32 + quad * 8);
      __builtin_amdgcn_s_setprio(1);
#pragma unroll
      for (int mi = 0; mi < 4; ++mi)
#pragma unroll
        for (int nj2 = 0; nj2 < 2; ++nj2)
          sacc[mi][nj2] = __builtin_amdgcn_mfma_f32_16x16x32_bf16(
              kf[nj2], qf[mi][kk], sacc[mi][nj2], 0, 0, 0);
      __builtin_amdgcn_s_setprio(0);
    }

    // V A-frags for this wave's key half: cols 32*h2 + quad*8 + j.
    // Independent of softmax -> issue before the VALU phase.
    short8 vf[4];
#pragma unroll
    for (int nd = 0; nd < 4; ++nd)
      vf[nd] = *(const short8*)(Vc + (nd * 16 + lan) * KPAD + h2 * 32 + quad * 8);

    // softmax in-register. Lane holds P^T[key = (2h2+nj2)*16+4quad+r][q=lan].
    // Pack: word j = 4*nj2 + r of ONE B-frag => phys col k' = 32h2+8quad+j
    // = pi'(key); V columns were written at pi'(key) -> contraction lines up.
    short8 pb[4];
#pragma unroll
    for (int mi = 0; mi < 4; ++mi) {
      float p[2][4];
#pragma unroll
      for (int nj2 = 0; nj2 < 2; ++nj2)
#pragma unroll
        for (int r = 0; r < 4; ++r) p[nj2][r] = EXP2(sacc[mi][nj2][r]);
      float s0 = 0.f, s1 = 0.f;
#pragma unroll
      for (int r = 0; r < 4; ++r) {
        s0 += p[0][r];
        s1 += p[1][r];
      }
      lrun[mi] += s0 + s1;
      const ushort2 w0 = pk_bf16(p[0][0], p[0][1]);
      const ushort2 w1 = pk_bf16(p[0][2], p[0][3]);
      const ushort2 w2 = pk_bf16(p[1][0], p[1][1]);
      const ushort2 w3 = pk_bf16(p[1][2], p[1][3]);
      union { short8 s8; ushort us[8]; } u;
      u.us[0] = w0.x; u.us[1] = w0.y; u.us[2] = w1.x; u.us[3] = w1.y;
      u.us[4] = w2.x; u.us[5] = w2.y; u.us[6] = w3.x; u.us[7] = w3.y;
      pb[mi] = u.s8;
    }

    // O^T += mfma(A=V^T[d][k'], B=P^T[q][k']): single kk (32-key contraction).
    __builtin_amdgcn_s_setprio(1);
#pragma unroll
    for (int mi = 0; mi < 4; ++mi)
#pragma unroll
      for (int nd = 0; nd < 4; ++nd)
        oacc[mi][nd] = __builtin_amdgcn_mfma_f32_16x16x32_bf16(
            vf[nd], pb[mi], oacc[mi][nd], 0, 0, 0);
    __builtin_amdgcn_s_setprio(0);

    // stage next tile into the other buffer, then the single per-kt barrier.
    if (kt < 31) {
      const int nxt = cur ^ 1;
      *(short8*)(KV[nxt] + rowA * KPAD + colq) = k0;
      *(short8*)(KV[nxt] + rowB * KPAD + colq) = k1;
      *(short8*)(KV[2 + nxt] + rowA * KPAD + colq) = v0;
      *(short8*)(KV[2 + nxt] + rowB * KPAD + colq) = v1;
      __syncthreads();
    }
  }

  // ---- key-half merge epilogue (partner = w^1, same g) ----
  // quad-reduce lrun (sum over the 4 quad groups; q = lan is quad-invariant)
#pragma unroll
  for (int mi = 0; mi < 4; ++mi) {
    lrun[mi] += __shfl_xor(lrun[mi], 16);
    lrun[mi] += __shfl_xor(lrun[mi], 32);
  }
  __syncthreads();  // K/V buffers dead; reuse as merge scratch
  float4* obuf = (float4*)&KV[0][0];          // [2 g][64 l][16 slots] = 32 KB
  float* lbuf = (float*)&KV[0][0] + 8192;     // [2 g][64 l][4 mi] = 2 KB
  if (h2 == 1) {
#pragma unroll
    for (int mi = 0; mi < 4; ++mi) {
#pragma unroll
      for (int nd = 0; nd < 4; ++nd) {
        const int fi = mi * 4 + nd;
        float4 t;
        t.x = oacc[mi][nd][0]; t.y = oacc[mi][nd][1];
        t.z = oacc[mi][nd][2]; t.w = oacc[mi][nd][3];
        obuf[(g * 64 + l) * 16 + ((fi + l) & 15)] = t;  // +l: bank spread
      }
      lbuf[(g * 64 + l) * 4 + mi] = lrun[mi];
    }
  }
  __syncthreads();
  if (h2 == 0) {
#pragma unroll
    for (int mi = 0; mi < 4; ++mi) {
      const float lt = lrun[mi] + lbuf[(g * 64 + l) * 4 + mi];
      const float inv = 1.0f / lt;
      const int qg = b * 2048 + q0 + g * 64 + mi * 16 + lan;
#pragma unroll
      for (int nd = 0; nd < 4; ++nd) {
        const int fi = mi * 4 + nd;
        const float4 t = obuf[(g * 64 + l) * 16 + ((fi + l) & 15)];
        ushort4 ov;
        ov.x = f2bf((oacc[mi][nd][0] + t.x) * inv);
        ov.y = f2bf((oacc[mi][nd][1] + t.y) * inv);
        ov.z = f2bf((oacc[mi][nd][2] + t.z) * inv);
        ov.w = f2bf((oacc[mi][nd][3] + t.w) * inv);
        *(ushort4*)(O + (size_t)qg * 1024 + h * 64 + nd * 16 + quad * 4) = ov;
      }
    }
  }
}

extern "C" void kernel_launch(void* const* d_in, const int* in_sizes, int n_in,
                              void* d_out, int out_size, void* d_ws, size_t ws_size,
                              hipStream_t stream) {
  const float* query = (const float*)d_in[0];
  const float* key_ = (const float*)d_in[1];
  const float* value = (const float*)d_in[2];
  const float* Wq = (const float*)d_in[3];
  const float* bq = (const float*)d_in[4];
  const float* Wk = (const float*)d_in[5];
  const float* bk = (const float*)d_in[6];
  const float* Wv = (const float*)d_in[7];
  const float* bv = (const float*)d_in[8];
  const float* Wo = (const float*)d_in[9];
  const float* bo = (const float*)d_in[10];
  float* out = (float*)d_out;

  u16* ws = (u16*)d_ws;
  u16* cWq = ws + 12582912;
  u16* cWk = ws + 13631488;
  u16* cWv = ws + 14680064;
  u16* cWo = ws + 15728640;
  u16* cbq = ws + 16777216;
  u16* cbk = ws + 16779264;
  u16* cbv = ws + 16781312;
  u16* cbo = ws + 16783360;
  u16* Qw = ws + 17301504;
  u16* Kw = ws + 21495808;
  u16* Vtw = ws + 25690112;
  u16* Ow = ws + 29884416;

  cvt_kernel<<<4100, 256, 0, stream>>>(Wq, Wk, Wv, Wo, bq, bk, bv, bo, ws);
  qkv_kernel<<<768, 256, 0, stream>>>(query, key_, value, cWq, cWk, cWv,
                                      cbq, cbk, cbv, Qw, Kw, Vtw);
  attn_kernel<<<dim3(16, 32), 256, 0, stream>>>(Qw, Kw, Vtw, Ow);
  proj_kernel<<<512, 256, 0, stream>>>(Ow, cWo, cbo, out);
}

// Round 10
// 217.248 us; speedup vs baseline: 1.1172x; 1.1172x over previous
//
#include <hip/hip_runtime.h>
#include <hip/hip_bf16.h>

// MultiHeadAttention: B=2, S=2048, H=16, d=64, D=1024. I/O fp32; compute bf16 MFMA.
// [cvt] fp32->bf16 -> [qkv] X@W^T+b (Q pre-scaled by 0.125*log2e; K row-major;
// V as [B,H,64,2048] keys pi'-permuted within 64-blocks) -> [attn] flash attn,
// swapped QK^T, in-register P, KEY-HALF split waves -> [proj] O@Wo^T+bo -> fp32.
// r19: REVERT to r16 (218.1us best). r17/r18 fused-X-cvt both regressed:
// fp32 X doubles the qkv per-XCD working set past 4MB L2 (FETCH 37->49MB) so
// in-loop staging runs at HBM latency; register-pipelining it parked waves
// (occupancy 27.8->15.9%). LAW: don't move streaming conversion into a
// barrier-synchronized compute loop when it pushes the working set past L2 —
// a separate streaming pass pays the bytes ONCE at full HBM efficiency.
// r13 (kept): XCD working-set swizzles — per-XCD concurrent set <=4MB.
// r14 (kept): gemm_tile one barrier/kt, NB=3 rotation, counted vmcnt.
// r16 (kept): attn key-half split (46us; all 4 SIMDs busy every kt).
// LAW (r7/r8): MFMA fragments are lane-granular gathers -> always read them from
// LDS; keep all global accesses contiguous (staging loads / scatter stores only).

typedef unsigned short u16;
typedef __attribute__((ext_vector_type(8))) short short8;   // 8 bf16 (MFMA A/B frag)
typedef __attribute__((ext_vector_type(4))) float floatx4;  // MFMA C/D frag

__device__ __forceinline__ float bf2f(u16 x) {
  return __uint_as_float(((unsigned)x) << 16);
}
__device__ __forceinline__ u16 f2bf(float f) {
  unsigned x = __float_as_uint(f);
  return (u16)((x + 0x7fffu + ((x >> 16) & 1u)) >> 16);  // RNE
}
__device__ __forceinline__ ushort2 pk_bf16(float a, float b) {
  __hip_bfloat162 h2 = __float22bfloat162_rn(make_float2(a, b));  // v_cvt_pk_bf16_f32
  ushort2 u;
  __builtin_memcpy(&u, &h2, 4);
  return u;
}
#if __has_builtin(__builtin_amdgcn_exp2f)
#define EXP2(x) __builtin_amdgcn_exp2f(x)
#else
#define EXP2(x) exp2f(x)
#endif
__device__ __forceinline__ void gll16(const u16* g, u16* lds) {
  __builtin_amdgcn_global_load_lds((const __attribute__((address_space(1))) void*)g,
                                   (__attribute__((address_space(3))) void*)lds,
                                   16, 0, 0);
}

// ---------------------------------------------------------------------------
// fp32 -> bf16 of all 11 inputs. 16388 blocks x 256 thr x 4 elem, exact cover.
// ---------------------------------------------------------------------------
__global__ __launch_bounds__(256) void cvt_kernel(
    const float* __restrict__ q, const float* __restrict__ k, const float* __restrict__ v,
    const float* __restrict__ wq, const float* __restrict__ wk,
    const float* __restrict__ wv, const float* __restrict__ wo,
    const float* __restrict__ bq, const float* __restrict__ bk,
    const float* __restrict__ bv, const float* __restrict__ bo,
    u16* __restrict__ ws) {
  const int i4 = (blockIdx.x * 256 + threadIdx.x) * 4;
  const float* src;
  u16* dst;
  int local;
  if (i4 < 4194304)        { src = q;  dst = ws;            local = i4; }
  else if (i4 < 8388608)   { src = k;  dst = ws + 4194304;  local = i4 - 4194304; }
  else if (i4 < 12582912)  { src = v;  dst = ws + 8388608;  local = i4 - 8388608; }
  else if (i4 < 13631488)  { src = wq; dst = ws + 12582912; local = i4 - 12582912; }
  else if (i4 < 14680064)  { src = wk; dst = ws + 13631488; local = i4 - 13631488; }
  else if (i4 < 15728640)  { src = wv; dst = ws + 14680064; local = i4 - 14680064; }
  else if (i4 < 16777216)  { src = wo; dst = ws + 15728640; local = i4 - 15728640; }
  else if (i4 < 16778240)  { src = bq; dst = ws + 16777216; local = i4 - 16777216; }
  else if (i4 < 16779264)  { src = bk; dst = ws + 16779264; local = i4 - 16778240; }
  else if (i4 < 16780288)  { src = bv; dst = ws + 16781312; local = i4 - 16779264; }
  else                     { src = bo; dst = ws + 16783360; local = i4 - 16780288; }
  const float4 f = *(const float4*)(src + local);
  ushort4 o;
  o.x = f2bf(f.x); o.y = f2bf(f.y); o.z = f2bf(f.z); o.w = f2bf(f.w);
  *(ushort4*)(dst + local) = o;
}

// ---------------------------------------------------------------------------
// GEMM tile: out[m][n] = (X[m][:].W[n][:] + bias[n]) * oscale
// MTILE x 128 tile, 256 thr (2x2 waves), BK=32, gll16 width-16 staging.
// r14 schedule: NB=3, stage-ahead 1, ONE s_barrier per kt, counted vmcnt(L).
// Region safety: between barrier(kt) and barrier(kt+1) the block reads buf
// kt%3 and writes buf (kt+1)%3 — disjoint (mod 3).
// mode 0: bf16 row-major. mode 1: bf16 [b][h][dd][s'] (pi'-key-permuted).
// mode 2: fp32 row-major.
// ---------------------------------------------------------------------------
template <int MTILE>
__device__ __forceinline__ void gemm_tile(
    const u16* __restrict__ X, const u16* __restrict__ W,
    const u16* __restrict__ bias, u16* __restrict__ out16, float* __restrict__ out32,
    int row0, int col0, int mode, float oscale, u16* As, u16* Bs) {
  constexpr int NI = MTILE / 32;      // A-frag repeats per wave (4 or 2)
  constexpr int ABUF = MTILE * 32;    // u16 per A buffer (4096 or 2048)
  const int tid = threadIdx.x;
  const int w = tid >> 6, l = tid & 63;
  const int lan = l & 15, quad = l >> 4;
  const int wm = w & 1, wn = w >> 1;

  floatx4 acc[NI][4];
#pragma unroll
  for (int i = 0; i < NI; ++i)
#pragma unroll
    for (int j = 0; j < 4; ++j) acc[i][j] = (floatx4)0.0f;

  const int r0 = tid >> 2, kq0 = tid & 3;
  const int r1 = (tid + 256) >> 2;
  const int woff = w * 512;
  const u16* Xa0 = X + (size_t)(row0 + r0) * 1024 + kq0 * 8;
  const u16* Xa1 = X + (size_t)(row0 + (MTILE == 128 ? r1 : r0)) * 1024 + kq0 * 8;
  const u16* Wb0 = W + (size_t)(col0 + r0) * 1024 + kq0 * 8;
  const u16* Wb1 = W + (size_t)(col0 + r1) * 1024 + kq0 * 8;

#define STAGE(buf, kt)                                           \
  do {                                                           \
    gll16(Xa0 + (kt) * 32, As + (buf) * ABUF + woff);            \
    if (MTILE == 128)                                            \
      gll16(Xa1 + (kt) * 32, As + (buf) * ABUF + 2048 + woff);   \
    gll16(Wb0 + (kt) * 32, Bs + (buf) * 4096 + woff);            \
    gll16(Wb1 + (kt) * 32, Bs + (buf) * 4096 + 2048 + woff);     \
  } while (0)

  STAGE(0, 0);
  int cur = 0;
  for (int kt = 0; kt < 32; ++kt) {
    if (kt < 31) {
      const int nb = cur == 2 ? 0 : cur + 1;  // (kt+1)%3
      STAGE(nb, kt + 1);
      // outstanding: L (tile kt, oldest) + L (tile kt+1) -> wait oldest L
      if (MTILE == 128)
        __asm__ volatile("s_waitcnt vmcnt(4)" ::: "memory");
      else
        __asm__ volatile("s_waitcnt vmcnt(3)" ::: "memory");
    } else {
      __asm__ volatile("s_waitcnt vmcnt(0)" ::: "memory");
    }
    __builtin_amdgcn_s_barrier();  // all waves' staging for tile kt visible

    const u16* Ab = As + cur * ABUF;
    const u16* Bb = Bs + cur * 4096;
    short8 af[NI], bfr[4];
#pragma unroll
    for (int i = 0; i < NI; ++i)
      af[i] = *(const short8*)(Ab + (wm * (MTILE / 2) + i * 16 + lan) * 32 + quad * 8);
#pragma unroll
    for (int j = 0; j < 4; ++j)
      bfr[j] = *(const short8*)(Bb + (wn * 64 + j * 16 + lan) * 32 + quad * 8);
    // no second barrier: compiler inserts lgkm waits for ds_read->MFMA; buffer
    // reuse safety comes from the mod-3 rotation (see header comment).
#pragma unroll
    for (int i = 0; i < NI; ++i)
#pragma unroll
      for (int j = 0; j < 4; ++j)
        acc[i][j] = __builtin_amdgcn_mfma_f32_16x16x32_bf16(af[i], bfr[j], acc[i][j], 0, 0, 0);
    cur = cur == 2 ? 0 : cur + 1;
  }
#undef STAGE

#pragma unroll
  for (int i = 0; i < NI; ++i) {
    const int mb = row0 + wm * (MTILE / 2) + i * 16 + quad * 4;
#pragma unroll
    for (int j = 0; j < 4; ++j) {
      const int n = col0 + wn * 64 + j * 16 + lan;
      const float bv = bf2f(bias[n]);
      if (mode == 0) {
#pragma unroll
        for (int r = 0; r < 4; ++r)
          out16[(size_t)(mb + r) * 1024 + n] = f2bf((acc[i][j][r] + bv) * oscale);
      } else if (mode == 1) {
        // V head-transposed + pi'-key-permuted: k=s&63 -> slot
        // 32*k[5] + 8*k[3:2] + 4*k[4] + k[1:0]  (key-half h=k[5] -> contiguous
        // cols 32h..32h+31). mb%4==0 -> r=k&3 in LOW bits -> ushort4 store.
        const int b = mb >> 11;
        const int h = n >> 6, dd = n & 63;
        u16* base = out16 + (size_t)((b * 16 + h) * 64 + dd) * 2048;
        const int s0 = mb & 2047;
        const int k0 = s0 & 63;
        const int sp0 = (s0 & ~63) | (((k0 >> 5) & 1) << 5) | (((k0 >> 2) & 3) << 3) |
                        (((k0 >> 4) & 1) << 2);
        ushort4 ov;
        ov.x = f2bf(acc[i][j][0] + bv);
        ov.y = f2bf(acc[i][j][1] + bv);
        ov.z = f2bf(acc[i][j][2] + bv);
        ov.w = f2bf(acc[i][j][3] + bv);
        *(ushort4*)(base + sp0) = ov;
      } else {
#pragma unroll
        for (int r = 0; r < 4; ++r)
          out32[(size_t)(mb + r) * 1024 + n] = acc[i][j][r] + bv;
      }
    }
  }
}

__global__ __launch_bounds__(256) void qkv_kernel(
    const u16* __restrict__ xq, const u16* __restrict__ xk, const u16* __restrict__ xv,
    const u16* __restrict__ Wq, const u16* __restrict__ Wk, const u16* __restrict__ Wv,
    const u16* __restrict__ bq, const u16* __restrict__ bk, const u16* __restrict__ bv,
    u16* __restrict__ Qo, u16* __restrict__ Ko, u16* __restrict__ Vto) {
  __shared__ __align__(16) u16 As[3 * 4096];
  __shared__ __align__(16) u16 Bs[3 * 4096];
  // r13 XCD grouping: all 8 col-blocks of one (which,tm) X-panel on ONE XCD.
  const int bx = blockIdx.x;           // 0..767
  const int xcd = bx & 7;
  const int j = bx >> 3;               // 0..95
  const int c = j & 7;                 // col block
  const int gidx = j >> 3;             // 0..11
  const int g = gidx * 8 + xcd;        // group = which*32 + tm, on XCD g%8
  const int which = g >> 5;            // 0=Q 1=K 2=V
  const int tile_m = g & 31;
  const int col0 = c * 128;
  const u16* X = which == 0 ? xq : (which == 1 ? xk : xv);
  const u16* W = which == 0 ? Wq : (which == 1 ? Wk : Wv);
  const u16* bias = which == 0 ? bq : (which == 1 ? bk : bv);
  u16* out = which == 0 ? Qo : (which == 1 ? Ko : Vto);
  const float C = 0.125f * 1.4426950408889634f;  // fold scale*log2e into Q
  gemm_tile<128>(X, W, bias, out, nullptr, tile_m * 128, col0, which == 2 ? 1 : 0,
                 which == 0 ? C : 1.0f, As, Bs);
}

__global__ __launch_bounds__(256) void proj_kernel(
    const u16* __restrict__ X, const u16* __restrict__ W,
    const u16* __restrict__ bias, float* __restrict__ out) {
  // 64x128 tiles -> 512 blocks = 2 blocks/CU. r13 XCD grouping: 8 tm-panels
  // (1MB) + full Wo (2MB) per XCD = 3MB < 4MB L2.
  __shared__ __align__(16) u16 As[3 * 2048];
  __shared__ __align__(16) u16 Bs[3 * 4096];
  const int bx = blockIdx.x;   // 0..511
  const int xcd = bx & 7;
  const int j = bx >> 3;       // 0..63
  const int c = j & 7;
  const int gidx = j >> 3;     // 0..7
  const int tm = xcd * 8 + gidx;
  gemm_tile<64>(X, W, bias, nullptr, out, tm * 64, c * 128, 2, 1.0f, As, Bs);
}

// ---------------------------------------------------------------------------
// Flash attention v12 (r16): swapped QK^T, in-register P, KEY-HALF split.
// grid 512 flat, 256 thr, 4 waves. Wave = (g = w>>1: 64 q rows, h = w&1: keys
// [32h, 32h+32) of EVERY tile). Per wave-kt (64q x 32keys):
//   S^T = mfma(A=K[key][dd], B=Q[q][dd])  16 MFMA, kf 4 b128 reads
//   p = exp2(S^T - 16); cvt_pk -> ONE PV B-frag per mi (permutation pi')
//   O^T += mfma(A=V^T[dd][k'], B=P^T)     16 MFMA, vf 4 b128 reads
// -> 8 b128 / 32 MFMA (2x reuse) with ALL 4 SIMDs active every kt.
// Fixed-max softmax => key-half partials directly addable: epilogue merge via
// LDS (h=1 waves dump unnorm oacc + lrun, h=0 partner w^1 adds, norms, stores).
// K/V LDS double-buffered, ONE barrier/kt; staging by all 256 threads.
// LDS: KV[4][64*72] = 36864 B; 2 blocks/CU (8 waves/CU).
// r13 XCD grouping: each XCD owns 4 complete bh -> K/V set 2MB, L2-resident.
// ---------------------------------------------------------------------------
#define FIXMAX 16.0f
#define KPAD 72
__global__ __launch_bounds__(256, 2) void attn_kernel(
    const u16* __restrict__ Q, const u16* __restrict__ K,
    const u16* __restrict__ Vt, u16* __restrict__ O) {
  __shared__ __align__(16) u16 KV[4][64 * KPAD];  // [0..1]=K dbuf, [2..3]=V dbuf
  const int tid = threadIdx.x;
  const int w = tid >> 6, l = tid & 63;
  const int lan = l & 15, quad = l >> 4;
  const int g = w >> 1;   // q-group: rows g*64 .. g*64+63
  const int h2 = w & 1;   // key half: keys 32*h2 .. 32*h2+31 of each tile
  // XCD grouping: flattened id -> (bh, qtile) with 4 full bh per XCD
  const int id = blockIdx.x + (blockIdx.y << 4);  // 0..511, xcd = id&7
  const int xcd = id & 7;
  const int jj = id >> 3;              // 0..63
  const int bh = xcd * 4 + (jj >> 4);  // 4 complete bh per XCD
  const int q0 = (jj & 15) * 128;
  const int b = bh >> 4, h = bh & 15;
  const u16* Qg = Q + (size_t)(b * 2048 + q0) * 1024 + h * 64;
  const u16* Kg = K + (size_t)(b * 2048) * 1024 + h * 64;
  const u16* Vg = Vt + (size_t)((b * 16 + h) * 64) * 2048;

  // Q B-frags direct from global: rows g*64 + mi*16 + lan (contiguous 64B rows)
  short8 qf[4][2];
#pragma unroll
  for (int mi = 0; mi < 4; ++mi)
#pragma unroll
    for (int kk = 0; kk < 2; ++kk)
      qf[mi][kk] = *(const short8*)(Qg + (size_t)(g * 64 + mi * 16 + lan) * 1024 +
                                    kk * 32 + quad * 8);

  float lrun[4] = {0.f, 0.f, 0.f, 0.f};
  floatx4 oacc[4][4];
#pragma unroll
  for (int mi = 0; mi < 4; ++mi)
#pragma unroll
    for (int nd = 0; nd < 4; ++nd) oacc[mi][nd] = (floatx4)0.0f;

  // staging maps: 64 rows x 8 chunks of 16B = 512 chunks, 2/thread (coalesced)
  const int rowA = tid >> 3, colq = (tid & 7) * 8;  // rows 0..31
  const int rowB = rowA + 32;                       // rows 32..63

  // prologue: tile 0 -> regs -> LDS buf 0
  short8 k0 = *(const short8*)(Kg + (size_t)rowA * 1024 + colq);
  short8 k1 = *(const short8*)(Kg + (size_t)rowB * 1024 + colq);
  short8 v0 = *(const short8*)(Vg + (size_t)rowA * 2048 + colq);
  short8 v1 = *(const short8*)(Vg + (size_t)rowB * 2048 + colq);
  *(short8*)(KV[0] + rowA * KPAD + colq) = k0;
  *(short8*)(KV[0] + rowB * KPAD + colq) = k1;
  *(short8*)(KV[2] + rowA * KPAD + colq) = v0;
  *(short8*)(KV[2] + rowB * KPAD + colq) = v1;
  __syncthreads();

  for (int kt = 0; kt < 32; ++kt) {
    const int cur = kt & 1;
    // issue next-tile global loads right after the barrier (all threads):
    // in flight across the compute phase, consumed by reg->LDS writes at end
    if (kt < 31) {
      const int kn = kt + 1;
      k0 = *(const short8*)(Kg + (size_t)(kn * 64 + rowA) * 1024 + colq);
      k1 = *(const short8*)(Kg + (size_t)(kn * 64 + rowB) * 1024 + colq);
      v0 = *(const short8*)(Vg + (size_t)rowA * 2048 + kn * 64 + colq);
      v1 = *(const short8*)(Vg + (size_t)rowB * 2048 + kn * 64 + colq);
    }
    const u16* Kc = KV[cur];
    const u16* Vc = KV[2 + cur];

    // S^T = mfma(A=K, B=Q): kf rows (2*h2+nj2)*16+lan, 2 b128 per kk.
    floatx4 sacc[4][2];
#pragma unroll
    for (int mi = 0; mi < 4; ++mi)
#pragma unroll
      for (int nj2 = 0; nj2 < 2; ++nj2) sacc[mi][nj2] = (floatx4)(-FIXMAX);
#pragma unroll
    for (int kk = 0; kk < 2; ++kk) {
      short8 kf[2];
#pragma unroll
      for (int nj2 = 0; nj2 < 2; ++nj2)
        kf[nj2] = *(const short8*)(Kc + ((2 * h2 + nj2) * 16 + lan) * KPAD +
                                   kk * 32 + quad * 8);
      __builtin_amdgcn_s_setprio(1);
#pragma unroll
      for (int mi = 0; mi < 4; ++mi)
#pragma unroll
        for (int nj2 = 0; nj2 < 2; ++nj2)
          sacc[mi][nj2] = __builtin_amdgcn_mfma_f32_16x16x32_bf16(
              kf[nj2], qf[mi][kk], sacc[mi][nj2], 0, 0, 0);
      __builtin_amdgcn_s_setprio(0);
    }

    // V A-frags for this wave's key half: cols 32*h2 + quad*8 + j.
    // Independent of softmax -> issue before the VALU phase.
    short8 vf[4];
#pragma unroll
    for (int nd = 0; nd < 4; ++nd)
      vf[nd] = *(const short8*)(Vc + (nd * 16 + lan) * KPAD + h2 * 32 + quad * 8);

    // softmax in-register. Lane holds P^T[key = (2h2+nj2)*16+4quad+r][q=lan].
    // Pack: word j = 4*nj2 + r of ONE B-frag => phys col k' = 32h2+8quad+j
    // = pi'(key); V columns were written at pi'(key) -> contraction lines up.
    short8 pb[4];
#pragma unroll
    for (int mi = 0; mi < 4; ++mi) {
      float p[2][4];
#pragma unroll
      for (int nj2 = 0; nj2 < 2; ++nj2)
#pragma unroll
        for (int r = 0; r < 4; ++r) p[nj2][r] = EXP2(sacc[mi][nj2][r]);
      float s0 = 0.f, s1 = 0.f;
#pragma unroll
      for (int r = 0; r < 4; ++r) {
        s0 += p[0][r];
        s1 += p[1][r];
      }
      lrun[mi] += s0 + s1;
      const ushort2 w0 = pk_bf16(p[0][0], p[0][1]);
      const ushort2 w1 = pk_bf16(p[0][2], p[0][3]);
      const ushort2 w2 = pk_bf16(p[1][0], p[1][1]);
      const ushort2 w3 = pk_bf16(p[1][2], p[1][3]);
      union { short8 s8; ushort us[8]; } u;
      u.us[0] = w0.x; u.us[1] = w0.y; u.us[2] = w1.x; u.us[3] = w1.y;
      u.us[4] = w2.x; u.us[5] = w2.y; u.us[6] = w3.x; u.us[7] = w3.y;
      pb[mi] = u.s8;
    }

    // O^T += mfma(A=V^T[d][k'], B=P^T[q][k']): single kk (32-key contraction).
    __builtin_amdgcn_s_setprio(1);
#pragma unroll
    for (int mi = 0; mi < 4; ++mi)
#pragma unroll
      for (int nd = 0; nd < 4; ++nd)
        oacc[mi][nd] = __builtin_amdgcn_mfma_f32_16x16x32_bf16(
            vf[nd], pb[mi], oacc[mi][nd], 0, 0, 0);
    __builtin_amdgcn_s_setprio(0);

    // stage next tile into the other buffer, then the single per-kt barrier.
    if (kt < 31) {
      const int nxt = cur ^ 1;
      *(short8*)(KV[nxt] + rowA * KPAD + colq) = k0;
      *(short8*)(KV[nxt] + rowB * KPAD + colq) = k1;
      *(short8*)(KV[2 + nxt] + rowA * KPAD + colq) = v0;
      *(short8*)(KV[2 + nxt] + rowB * KPAD + colq) = v1;
      __syncthreads();
    }
  }

  // ---- key-half merge epilogue (partner = w^1, same g) ----
  // quad-reduce lrun (sum over the 4 quad groups; q = lan is quad-invariant)
#pragma unroll
  for (int mi = 0; mi < 4; ++mi) {
    lrun[mi] += __shfl_xor(lrun[mi], 16);
    lrun[mi] += __shfl_xor(lrun[mi], 32);
  }
  __syncthreads();  // K/V buffers dead; reuse as merge scratch
  float4* obuf = (float4*)&KV[0][0];          // [2 g][64 l][16 slots] = 32 KB
  float* lbuf = (float*)&KV[0][0] + 8192;     // [2 g][64 l][4 mi] = 2 KB
  if (h2 == 1) {
#pragma unroll
    for (int mi = 0; mi < 4; ++mi) {
#pragma unroll
      for (int nd = 0; nd < 4; ++nd) {
        const int fi = mi * 4 + nd;
        float4 t;
        t.x = oacc[mi][nd][0]; t.y = oacc[mi][nd][1];
        t.z = oacc[mi][nd][2]; t.w = oacc[mi][nd][3];
        obuf[(g * 64 + l) * 16 + ((fi + l) & 15)] = t;  // +l: bank spread
      }
      lbuf[(g * 64 + l) * 4 + mi] = lrun[mi];
    }
  }
  __syncthreads();
  if (h2 == 0) {
#pragma unroll
    for (int mi = 0; mi < 4; ++mi) {
      const float lt = lrun[mi] + lbuf[(g * 64 + l) * 4 + mi];
      const float inv = 1.0f / lt;
      const int qg = b * 2048 + q0 + g * 64 + mi * 16 + lan;
#pragma unroll
      for (int nd = 0; nd < 4; ++nd) {
        const int fi = mi * 4 + nd;
        const float4 t = obuf[(g * 64 + l) * 16 + ((fi + l) & 15)];
        ushort4 ov;
        ov.x = f2bf((oacc[mi][nd][0] + t.x) * inv);
        ov.y = f2bf((oacc[mi][nd][1] + t.y) * inv);
        ov.z = f2bf((oacc[mi][nd][2] + t.z) * inv);
        ov.w = f2bf((oacc[mi][nd][3] + t.w) * inv);
        *(ushort4*)(O + (size_t)qg * 1024 + h * 64 + nd * 16 + quad * 4) = ov;
      }
    }
  }
}

extern "C" void kernel_launch(void* const* d_in, const int* in_sizes, int n_in,
                              void* d_out, int out_size, void* d_ws, size_t ws_size,
                              hipStream_t stream) {
  const float* query = (const float*)d_in[0];
  const float* key_ = (const float*)d_in[1];
  const float* value = (const float*)d_in[2];
  const float* Wq = (const float*)d_in[3];
  const float* bq = (const float*)d_in[4];
  const float* Wk = (const float*)d_in[5];
  const float* bk = (const float*)d_in[6];
  const float* Wv = (const float*)d_in[7];
  const float* bv = (const float*)d_in[8];
  const float* Wo = (const float*)d_in[9];
  const float* bo = (const float*)d_in[10];
  float* out = (float*)d_out;

  u16* ws = (u16*)d_ws;
  u16* Xq = ws;
  u16* Xk = ws + 4194304;
  u16* Xv = ws + 8388608;
  u16* cWq = ws + 12582912;
  u16* cWk = ws + 13631488;
  u16* cWv = ws + 14680064;
  u16* cWo = ws + 15728640;
  u16* cbq = ws + 16777216;
  u16* cbk = ws + 16779264;
  u16* cbv = ws + 16781312;
  u16* cbo = ws + 16783360;
  u16* Qw = ws + 17301504;
  u16* Kw = ws + 21495808;
  u16* Vtw = ws + 25690112;
  u16* Ow = ws + 29884416;

  cvt_kernel<<<16388, 256, 0, stream>>>(query, key_, value, Wq, Wk, Wv, Wo,
                                        bq, bk, bv, bo, ws);
  qkv_kernel<<<768, 256, 0, stream>>>(Xq, Xk, Xv, cWq, cWk, cWv, cbq, cbk, cbv,
                                      Qw, Kw, Vtw);
  attn_kernel<<<dim3(16, 32), 256, 0, stream>>>(Qw, Kw, Vtw, Ow);
  proj_kernel<<<512, 256, 0, stream>>>(Ow, cWo, cbo, out);
}